// Round 17
// baseline (401.944 us; speedup 1.0000x reference)
//
#include <hip/hip_runtime.h>
#include <hip/hip_bf16.h>

typedef unsigned short ushort_t;
typedef unsigned char uchar_t;
typedef __attribute__((ext_vector_type(4))) int int4v;
typedef __attribute__((ext_vector_type(2))) unsigned int uint2v;

#define NQ      2048
#define ND      512
#define NDB     100000
#define TOPK    10
#define NCHUNK  98
#define CHUNK_N 1024                  // 8 tiles * 128
#define NPAD    (NCHUNK * CHUNK_N)    // 100352 >= 100000
#define QTILES  (NQ / 128)            // 16
#define NTILES  (CHUNK_N / 128)       // 8
#define NWG     (NCHUNK * QTILES)     // 1568 = 8 * 196
#define PERXCD  (NWG / 8)             // 196
#define QSCALE  400.0f
#define QINV    (1.0f / (QSCALE * QSCALE))
#define IMIN    (-2147483647 - 1)

// async global->LDS, 16B per lane, wave-uniform LDS base + lane*16
#define GL2LDS(gp, lp) __builtin_amdgcn_global_load_lds(                      \
    (const __attribute__((address_space(1))) void*)(gp),                     \
    (__attribute__((address_space(3))) void*)(lp), 16, 0, 0)

// ---------- row L2-normalize, fp32 -> i8 (x*400, RNE, clamp +-127); zero pad rows ----------
__global__ void normalize_rows_i8(const float* __restrict__ in, uchar_t* __restrict__ out,
                                  int nvalid, int ntotal) {
    int row  = blockIdx.x * 4 + (threadIdx.x >> 6);
    int lane = threadIdx.x & 63;
    if (row >= ntotal) return;
    uint2v pk;
    if (row >= nvalid) {
        pk[0] = 0u; pk[1] = 0u;
    } else {
        const float4* src = reinterpret_cast<const float4*>(in + (size_t)row * ND);
        float4 v0 = src[lane * 2];
        float4 v1 = src[lane * 2 + 1];
        float s = v0.x*v0.x + v0.y*v0.y + v0.z*v0.z + v0.w*v0.w
                + v1.x*v1.x + v1.y*v1.y + v1.z*v1.z + v1.w*v1.w;
        #pragma unroll
        for (int off = 32; off; off >>= 1) s += __shfl_xor(s, off, 64);
        float r = rsqrtf(s) * QSCALE;
        float f[8] = { v0.x, v0.y, v0.z, v0.w, v1.x, v1.y, v1.z, v1.w };
        unsigned b[8];
        #pragma unroll
        for (int i = 0; i < 8; ++i) {
            int q = (int)rintf(f[i] * r);
            q = q > 127 ? 127 : (q < -127 ? -127 : q);
            b[i] = (unsigned)q & 0xFFu;
        }
        pk[0] = b[0] | (b[1] << 8) | (b[2] << 16) | (b[3] << 24);
        pk[1] = b[4] | (b[5] << 8) | (b[6] << 16) | (b[7] << 24);
    }
    *reinterpret_cast<uint2v*>(out + (size_t)row * ND + lane * 8) = pk;
}

__device__ inline void topk_insert_i(int (&top)[TOPK], int x) {
    #pragma unroll
    for (int i = 0; i < TOPK; ++i) {
        int mx = top[i] > x ? top[i] : x;
        int mn = top[i] > x ? x : top[i];
        top[i] = mx;
        x = mn;
    }
}

// ---------- fused i8 GEMM + per-chunk top-10: 8 waves x (32q x 64n) ----------
// 512 threads, 8 waves; wave wv = q-group (wv>>1) x n-half (wv&1).
// vs R15 (16q x 128n): B-frag reads per MAC halved -> 6 b128 per 8 MFMA per
// K-step (was 9). Same 128x64B staged tiles + swizzle + 2-barrier K-step (R15
// verbatim; R16's issue-early overlap thrashed L2 and regressed).
// SWAPPED mfma(B,A): acc[qs][ns][r] = dot_i32[n = nh*64+ns*16+lhi*4+r][q].
__global__ __launch_bounds__(512, 8)
void knn_chunk(const uchar_t* __restrict__ qb, const uchar_t* __restrict__ dbb,
               int* __restrict__ partial) {
    // XCD swizzle: 16 consecutive logicals (same B-chunk) land on the same XCD
    const int logical = (blockIdx.x & 7) * PERXCD + (blockIdx.x >> 3);
    const int qt = logical & (QTILES - 1);
    const int nc = logical >> 4;       // QTILES == 16
    const int t = threadIdx.x, lane = t & 63, wv = t >> 6;
    const int l15 = lane & 15;
    const int qg = wv >> 1, nh = wv & 1;

    __shared__ __align__(16) uchar_t As[128 * 64];    // 8 KB
    __shared__ __align__(16) uchar_t Bs[128 * 64];    // 8 KB

    int top[2][TOPK];
    #pragma unroll
    for (int qs = 0; qs < 2; ++qs)
        #pragma unroll
        for (int i = 0; i < TOPK; ++i) top[qs][i] = IMIN;

    const size_t nchunkbase = (size_t)nc * CHUNK_N;
    const uchar_t* aseg = qb + (size_t)(qt * 128) * ND;

    // ---- hoisted per-lane invariants ----
    // staging: thread t covers chunk t of each matrix (512 chunks = 128 rows x 4)
    const int srow = t >> 2;
    const int scol = (t & 3) ^ ((srow >> 1) & 3);       // inverse swizzle on global source
    const int soff = srow * ND + scol * 16;
    const int doff = t * 16;
    // frag reads: swizzle slot depends only on l15 -> one base + imm offsets
    const int cgrp = lane >> 4;                          // logical 16B chunk in row
    const int slot = (cgrp ^ ((l15 >> 1) & 3)) * 16;
    const int aoff = (qg * 32 + l15) * 64 + slot;        // A rows qg*32 + qs*16 + l15 (qs imm)
    const int boff = (nh * 64 + l15) * 64 + slot;        // B rows nh*64 + ns*16 + l15 (ns imm)

    for (int nt = 0; nt < NTILES; ++nt) {
        const uchar_t* bseg = dbb + (nchunkbase + nt * 128) * ND;
        int4v acc[2][4];
        #pragma unroll
        for (int a = 0; a < 2; ++a)
            #pragma unroll
            for (int b = 0; b < 4; ++b) acc[a][b] = (int4v){0, 0, 0, 0};

        #pragma unroll
        for (int ks = 0; ks < 8; ++ks) {
            const int kbase = ks * 64;             // compile-time after unroll
            __syncthreads();   // previous K-step's frags consumed
            GL2LDS(aseg + soff + kbase, As + doff);
            GL2LDS(bseg + soff + kbase, Bs + doff);
            __syncthreads();   // K-slice staged (implicit vmcnt(0))
            int4v af0 = *reinterpret_cast<const int4v*>(As + aoff);
            int4v af1 = *reinterpret_cast<const int4v*>(As + aoff + 1024);
            int4v bf0 = *reinterpret_cast<const int4v*>(Bs + boff);
            int4v bf1 = *reinterpret_cast<const int4v*>(Bs + boff + 1024);
            int4v bf2 = *reinterpret_cast<const int4v*>(Bs + boff + 2048);
            int4v bf3 = *reinterpret_cast<const int4v*>(Bs + boff + 3072);
            acc[0][0] = __builtin_amdgcn_mfma_i32_16x16x64_i8(bf0, af0, acc[0][0], 0, 0, 0);
            acc[0][1] = __builtin_amdgcn_mfma_i32_16x16x64_i8(bf1, af0, acc[0][1], 0, 0, 0);
            acc[0][2] = __builtin_amdgcn_mfma_i32_16x16x64_i8(bf2, af0, acc[0][2], 0, 0, 0);
            acc[0][3] = __builtin_amdgcn_mfma_i32_16x16x64_i8(bf3, af0, acc[0][3], 0, 0, 0);
            acc[1][0] = __builtin_amdgcn_mfma_i32_16x16x64_i8(bf0, af1, acc[1][0], 0, 0, 0);
            acc[1][1] = __builtin_amdgcn_mfma_i32_16x16x64_i8(bf1, af1, acc[1][1], 0, 0, 0);
            acc[1][2] = __builtin_amdgcn_mfma_i32_16x16x64_i8(bf2, af1, acc[1][2], 0, 0, 0);
            acc[1][3] = __builtin_amdgcn_mfma_i32_16x16x64_i8(bf3, af1, acc[1][3], 0, 0, 0);
        }

        // integer selection: per qs, 16 candidates for this thread's fixed query
        #pragma unroll
        for (int qs = 0; qs < 2; ++qs) {
            int m = acc[qs][0][0];
            #pragma unroll
            for (int ns = 0; ns < 4; ++ns)
                #pragma unroll
                for (int r = 0; r < 4; ++r)
                    m = m > acc[qs][ns][r] ? m : acc[qs][ns][r];
            if (m > top[qs][TOPK - 1]) {
                #pragma unroll
                for (int ns = 0; ns < 4; ++ns)
                    #pragma unroll
                    for (int r = 0; r < 4; ++r) {
                        int v = acc[qs][ns][r];
                        if (v > top[qs][TOPK - 1]) topk_insert_i(top[qs], v);
                    }
            }
        }
    }

    // butterfly merge across the 4 lanes sharing each query (lane ^ 16, lane ^ 32)
    #pragma unroll
    for (int qs = 0; qs < 2; ++qs) {
        #pragma unroll
        for (int step = 16; step <= 32; step <<= 1) {
            int other[TOPK];
            #pragma unroll
            for (int i = 0; i < TOPK; ++i) other[i] = __shfl_xor(top[qs][i], step, 64);
            #pragma unroll
            for (int i = 0; i < TOPK; ++i)
                if (other[i] > top[qs][TOPK - 1]) topk_insert_i(top[qs], other[i]);
        }
    }

    // lanes 0..15: per-query top-10 over this wave's n-half; slot = (nc, nh)
    if ((lane >> 4) == 0) {
        #pragma unroll
        for (int qs = 0; qs < 2; ++qs) {
            const int q = qt * 128 + qg * 32 + qs * 16 + l15;
            int* dst = partial + (((size_t)(nc * 2 + nh)) * NQ + q) * TOPK;
            #pragma unroll
            for (int i = 0; i < TOPK; ++i) dst[i] = top[qs][i];
        }
    }
}

// ---------- merge 2*NCHUNK slots per query (int domain), emit k-th sq distance ----------
__global__ void final_merge(const int* __restrict__ partial, float* __restrict__ out) {
    const int q = blockIdx.x * 4 + (threadIdx.x >> 6);
    const int lane = threadIdx.x & 63;
    if (q >= NQ) return;
    int top[TOPK];
    #pragma unroll
    for (int i = 0; i < TOPK; ++i) top[i] = IMIN;
    for (int c = lane; c < 2 * NCHUNK; c += 64) {
        const int* p = partial + ((size_t)c * NQ + q) * TOPK;
        #pragma unroll
        for (int i = 0; i < TOPK; ++i) {
            int x = p[i];
            if (x > top[TOPK - 1]) topk_insert_i(top, x);
        }
    }
    #pragma unroll
    for (int step = 1; step <= 32; step <<= 1) {
        int other[TOPK];
        #pragma unroll
        for (int i = 0; i < TOPK; ++i) other[i] = __shfl_xor(top[i], step, 64);
        #pragma unroll
        for (int i = 0; i < TOPK; ++i)
            if (other[i] > top[TOPK - 1]) topk_insert_i(top, other[i]);
    }
    if (lane == 0) out[q] = 2.0f - 2.0f * ((float)top[TOPK - 1] * QINV);
}

extern "C" void kernel_launch(void* const* d_in, const int* in_sizes, int n_in,
                              void* d_out, int out_size, void* d_ws, size_t ws_size,
                              hipStream_t stream) {
    const float* features = (const float*)d_in[0];
    const float* dbf      = (const float*)d_in[2];
    float* out = (float*)d_out;

    uchar_t* dbb = (uchar_t*)d_ws;                           // [NPAD][512] i8       ~51.4 MB
    uchar_t* qbn = dbb + (size_t)NPAD * ND;                  // [2048][512] i8       ~1 MB
    int* partial = (int*)(qbn + (size_t)NQ * ND);            // [2*NCHUNK][2048][10] ~16.1 MB

    normalize_rows_i8<<<NPAD / 4, 256, 0, stream>>>(dbf, dbb, NDB, NPAD);
    normalize_rows_i8<<<NQ / 4, 256, 0, stream>>>(features, qbn, NQ, NQ);
    knn_chunk<<<NWG, 512, 0, stream>>>(qbn, dbb, partial);
    final_merge<<<NQ / 4, 256, 0, stream>>>(partial, out);
}

// Round 18
// 304.004 us; speedup vs baseline: 1.3222x; 1.3222x over previous
//
#include <hip/hip_runtime.h>
#include <hip/hip_bf16.h>

typedef unsigned short ushort_t;
typedef unsigned char uchar_t;
typedef __attribute__((ext_vector_type(4))) int int4v;
typedef __attribute__((ext_vector_type(2))) unsigned int uint2v;

#define NQ      2048
#define ND      512
#define NDB     100000
#define TOPK    10
#define NCHUNK  98
#define CHUNK_N 1024                  // 8 tiles * 128
#define NPAD    (NCHUNK * CHUNK_N)    // 100352 >= 100000
#define QTILES  (NQ / 128)            // 16
#define NTILES  (CHUNK_N / 128)       // 8
#define NWG     (NCHUNK * QTILES)     // 1568 = 8 * 196
#define PERXCD  (NWG / 8)             // 196
#define QSCALE  400.0f
#define QINV    (1.0f / (QSCALE * QSCALE))
#define IMIN    (-2147483647 - 1)

// async global->LDS, 16B per lane, wave-uniform LDS base + lane*16
#define GL2LDS(gp, lp) __builtin_amdgcn_global_load_lds(                      \
    (const __attribute__((address_space(1))) void*)(gp),                     \
    (__attribute__((address_space(3))) void*)(lp), 16, 0, 0)

// ---------- row L2-normalize, fp32 -> i8 (x*400, RNE, clamp +-127); zero pad rows ----------
__global__ void normalize_rows_i8(const float* __restrict__ in, uchar_t* __restrict__ out,
                                  int nvalid, int ntotal) {
    int row  = blockIdx.x * 4 + (threadIdx.x >> 6);
    int lane = threadIdx.x & 63;
    if (row >= ntotal) return;
    uint2v pk;
    if (row >= nvalid) {
        pk[0] = 0u; pk[1] = 0u;
    } else {
        const float4* src = reinterpret_cast<const float4*>(in + (size_t)row * ND);
        float4 v0 = src[lane * 2];
        float4 v1 = src[lane * 2 + 1];
        float s = v0.x*v0.x + v0.y*v0.y + v0.z*v0.z + v0.w*v0.w
                + v1.x*v1.x + v1.y*v1.y + v1.z*v1.z + v1.w*v1.w;
        #pragma unroll
        for (int off = 32; off; off >>= 1) s += __shfl_xor(s, off, 64);
        float r = rsqrtf(s) * QSCALE;
        float f[8] = { v0.x, v0.y, v0.z, v0.w, v1.x, v1.y, v1.z, v1.w };
        unsigned b[8];
        #pragma unroll
        for (int i = 0; i < 8; ++i) {
            int q = (int)rintf(f[i] * r);
            q = q > 127 ? 127 : (q < -127 ? -127 : q);
            b[i] = (unsigned)q & 0xFFu;
        }
        pk[0] = b[0] | (b[1] << 8) | (b[2] << 16) | (b[3] << 24);
        pk[1] = b[4] | (b[5] << 8) | (b[6] << 16) | (b[7] << 24);
    }
    *reinterpret_cast<uint2v*>(out + (size_t)row * ND + lane * 8) = pk;
}

__device__ inline void topk_insert_i(int (&top)[TOPK], int x) {
    #pragma unroll
    for (int i = 0; i < TOPK; ++i) {
        int mx = top[i] > x ? top[i] : x;
        int mn = top[i] > x ? x : top[i];
        top[i] = mx;
        x = mn;
    }
}

// ---------- fused i8 GEMM + top-10: R15 structure, A-panel in REGISTERS ----------
// 512 threads, 8 waves; wave wv owns queries [wv*16, +16) x all 128 n of the tile.
// A panel: af[8] int4v (32 VGPR) = this wave's 16 q-rows x K=512, loaded ONCE from
// global (equiv to the LDS-swizzle path: row = qt*128+wv*16+l15, col = cgrp*16 within
// each 64-B k-slice). Per K-step: sync -> 1 gl2lds (B ONLY) -> sync -> 8 bf + 8 MFMA.
// Halves staging issues + vmcnt drain vs R15; LDS = 8 KB. Single top[10] (R17's
// doubled state spilled to scratch).
__global__ __launch_bounds__(512, 6)
void knn_chunk(const uchar_t* __restrict__ qb, const uchar_t* __restrict__ dbb,
               int* __restrict__ partial) {
    // XCD swizzle: 16 consecutive logicals (same B-chunk) land on the same XCD
    const int logical = (blockIdx.x & 7) * PERXCD + (blockIdx.x >> 3);
    const int qt = logical & (QTILES - 1);
    const int nc = logical >> 4;       // QTILES == 16
    const int t = threadIdx.x, lane = t & 63, wv = t >> 6;
    const int l15 = lane & 15;
    const int cgrp = lane >> 4;        // logical 16B chunk in a 64-B k-slice

    __shared__ __align__(16) uchar_t Bs[128 * 64];    // 8 KB

    // ---- A panel in registers: af[ks] = 16 B of row (qt*128+wv*16+l15), k-slice ks
    int4v af[8];
    {
        const uchar_t* ap = qb + (size_t)(qt * 128 + wv * 16 + l15) * ND + cgrp * 16;
        #pragma unroll
        for (int ks = 0; ks < 8; ++ks)
            af[ks] = *reinterpret_cast<const int4v*>(ap + ks * 64);
    }

    int top[TOPK];
    #pragma unroll
    for (int i = 0; i < TOPK; ++i) top[i] = IMIN;

    const size_t nchunkbase = (size_t)nc * CHUNK_N;

    // ---- hoisted per-lane invariants (B staging + B frag reads, R15-identical) ----
    const int srow = t >> 2;
    const int scol = (t & 3) ^ ((srow >> 1) & 3);       // inverse swizzle on global source
    const int soff = srow * ND + scol * 16;
    const int doff = t * 16;
    const int slot = (cgrp ^ ((l15 >> 1) & 3)) * 16;
    const int boff = l15 * 64 + slot;                    // B row = ns*16 + l15 (ns via imm)

    for (int nt = 0; nt < NTILES; ++nt) {
        const uchar_t* bseg = dbb + (nchunkbase + nt * 128) * ND;
        int4v acc[8];
        #pragma unroll
        for (int b = 0; b < 8; ++b) acc[b] = (int4v){0, 0, 0, 0};

        #pragma unroll
        for (int ks = 0; ks < 8; ++ks) {
            const int kbase = ks * 64;             // compile-time after unroll
            __syncthreads();   // previous K-step's frags consumed
            GL2LDS(bseg + soff + kbase, Bs + doff);
            __syncthreads();   // K-slice staged (implicit vmcnt(0))
            {
                int4v bf0 = *reinterpret_cast<const int4v*>(Bs + boff);
                int4v bf1 = *reinterpret_cast<const int4v*>(Bs + boff + 1024);
                int4v bf2 = *reinterpret_cast<const int4v*>(Bs + boff + 2048);
                int4v bf3 = *reinterpret_cast<const int4v*>(Bs + boff + 3072);
                acc[0] = __builtin_amdgcn_mfma_i32_16x16x64_i8(bf0, af[ks], acc[0], 0, 0, 0);
                acc[1] = __builtin_amdgcn_mfma_i32_16x16x64_i8(bf1, af[ks], acc[1], 0, 0, 0);
                acc[2] = __builtin_amdgcn_mfma_i32_16x16x64_i8(bf2, af[ks], acc[2], 0, 0, 0);
                acc[3] = __builtin_amdgcn_mfma_i32_16x16x64_i8(bf3, af[ks], acc[3], 0, 0, 0);
            }
            {
                int4v bf4 = *reinterpret_cast<const int4v*>(Bs + boff + 4096);
                int4v bf5 = *reinterpret_cast<const int4v*>(Bs + boff + 5120);
                int4v bf6 = *reinterpret_cast<const int4v*>(Bs + boff + 6144);
                int4v bf7 = *reinterpret_cast<const int4v*>(Bs + boff + 7168);
                acc[4] = __builtin_amdgcn_mfma_i32_16x16x64_i8(bf4, af[ks], acc[4], 0, 0, 0);
                acc[5] = __builtin_amdgcn_mfma_i32_16x16x64_i8(bf5, af[ks], acc[5], 0, 0, 0);
                acc[6] = __builtin_amdgcn_mfma_i32_16x16x64_i8(bf6, af[ks], acc[6], 0, 0, 0);
                acc[7] = __builtin_amdgcn_mfma_i32_16x16x64_i8(bf7, af[ks], acc[7], 0, 0, 0);
            }
        }

        // integer selection: 32 candidates for this thread's single query
        int m = acc[0][0];
        #pragma unroll
        for (int ns = 0; ns < 8; ++ns)
            #pragma unroll
            for (int r = 0; r < 4; ++r)
                m = m > acc[ns][r] ? m : acc[ns][r];
        if (m > top[TOPK - 1]) {
            #pragma unroll
            for (int ns = 0; ns < 8; ++ns)
                #pragma unroll
                for (int r = 0; r < 4; ++r) {
                    int v = acc[ns][r];
                    if (v > top[TOPK - 1]) topk_insert_i(top, v);
                }
        }
    }

    // butterfly merge across the 4 lanes sharing each query (lane ^ 16, lane ^ 32)
    #pragma unroll
    for (int step = 16; step <= 32; step <<= 1) {
        int other[TOPK];
        #pragma unroll
        for (int i = 0; i < TOPK; ++i) other[i] = __shfl_xor(top[i], step, 64);
        #pragma unroll
        for (int i = 0; i < TOPK; ++i)
            if (other[i] > top[TOPK - 1]) topk_insert_i(top, other[i]);
    }

    // lanes 0..15 hold the final per-query top-10 for q = qt*128 + wv*16 + l15
    if (cgrp == 0) {
        const int q = qt * 128 + wv * 16 + l15;
        int* dst = partial + ((size_t)nc * NQ + q) * TOPK;
        #pragma unroll
        for (int i = 0; i < TOPK; ++i) dst[i] = top[i];
    }
}

// ---------- merge NCHUNK chunks per query (int domain), emit k-th squared distance ----------
__global__ void final_merge(const int* __restrict__ partial, float* __restrict__ out) {
    const int q = blockIdx.x * 4 + (threadIdx.x >> 6);
    const int lane = threadIdx.x & 63;
    if (q >= NQ) return;
    int top[TOPK];
    #pragma unroll
    for (int i = 0; i < TOPK; ++i) top[i] = IMIN;
    for (int c = lane; c < NCHUNK; c += 64) {
        const int* p = partial + ((size_t)c * NQ + q) * TOPK;
        #pragma unroll
        for (int i = 0; i < TOPK; ++i) {
            int x = p[i];
            if (x > top[TOPK - 1]) topk_insert_i(top, x);
        }
    }
    #pragma unroll
    for (int step = 1; step <= 32; step <<= 1) {
        int other[TOPK];
        #pragma unroll
        for (int i = 0; i < TOPK; ++i) other[i] = __shfl_xor(top[i], step, 64);
        #pragma unroll
        for (int i = 0; i < TOPK; ++i)
            if (other[i] > top[TOPK - 1]) topk_insert_i(top, other[i]);
    }
    if (lane == 0) out[q] = 2.0f - 2.0f * ((float)top[TOPK - 1] * QINV);
}

extern "C" void kernel_launch(void* const* d_in, const int* in_sizes, int n_in,
                              void* d_out, int out_size, void* d_ws, size_t ws_size,
                              hipStream_t stream) {
    const float* features = (const float*)d_in[0];
    const float* dbf      = (const float*)d_in[2];
    float* out = (float*)d_out;

    uchar_t* dbb = (uchar_t*)d_ws;                           // [NPAD][512] i8     ~51.4 MB
    uchar_t* qbn = dbb + (size_t)NPAD * ND;                  // [2048][512] i8     ~1 MB
    int* partial = (int*)(qbn + (size_t)NQ * ND);            // [NCHUNK][2048][10] ~8.0 MB

    normalize_rows_i8<<<NPAD / 4, 256, 0, stream>>>(dbf, dbb, NDB, NPAD);
    normalize_rows_i8<<<NQ / 4, 256, 0, stream>>>(features, qbn, NQ, NQ);
    knn_chunk<<<NWG, 512, 0, stream>>>(qbn, dbb, partial);
    final_merge<<<NQ / 4, 256, 0, stream>>>(partial, out);
}

// Round 19
// 303.801 us; speedup vs baseline: 1.3230x; 1.0007x over previous
//
#include <hip/hip_runtime.h>
#include <hip/hip_bf16.h>

typedef unsigned short ushort_t;
typedef unsigned char uchar_t;
typedef __attribute__((ext_vector_type(4))) int int4v;
typedef __attribute__((ext_vector_type(2))) unsigned int uint2v;

#define NQ      2048
#define ND      512
#define NDB     100000
#define TOPK    10
#define NCHUNK  98
#define CHUNK_N 1024                  // 8 tiles * 128
#define NPAD    (NCHUNK * CHUNK_N)    // 100352 >= 100000
#define QTILES  (NQ / 128)            // 16
#define NTILES  (CHUNK_N / 128)       // 8
#define NWG     (NCHUNK * QTILES)     // 1568 = 8 * 196
#define PERXCD  (NWG / 8)             // 196
#define QSCALE  400.0f
#define QINV    (1.0f / (QSCALE * QSCALE))
#define IMIN    (-2147483647 - 1)

// async global->LDS, 16B per lane, wave-uniform LDS base + lane*16
#define GL2LDS(gp, lp) __builtin_amdgcn_global_load_lds(                      \
    (const __attribute__((address_space(1))) void*)(gp),                     \
    (__attribute__((address_space(3))) void*)(lp), 16, 0, 0)

// ---------- row L2-normalize, fp32 -> i8 (x*400, RNE, clamp +-127); zero pad rows ----------
__global__ void normalize_rows_i8(const float* __restrict__ in, uchar_t* __restrict__ out,
                                  int nvalid, int ntotal) {
    int row  = blockIdx.x * 4 + (threadIdx.x >> 6);
    int lane = threadIdx.x & 63;
    if (row >= ntotal) return;
    uint2v pk;
    if (row >= nvalid) {
        pk[0] = 0u; pk[1] = 0u;
    } else {
        const float4* src = reinterpret_cast<const float4*>(in + (size_t)row * ND);
        float4 v0 = src[lane * 2];
        float4 v1 = src[lane * 2 + 1];
        float s = v0.x*v0.x + v0.y*v0.y + v0.z*v0.z + v0.w*v0.w
                + v1.x*v1.x + v1.y*v1.y + v1.z*v1.z + v1.w*v1.w;
        #pragma unroll
        for (int off = 32; off; off >>= 1) s += __shfl_xor(s, off, 64);
        float r = rsqrtf(s) * QSCALE;
        float f[8] = { v0.x, v0.y, v0.z, v0.w, v1.x, v1.y, v1.z, v1.w };
        unsigned b[8];
        #pragma unroll
        for (int i = 0; i < 8; ++i) {
            int q = (int)rintf(f[i] * r);
            q = q > 127 ? 127 : (q < -127 ? -127 : q);
            b[i] = (unsigned)q & 0xFFu;
        }
        pk[0] = b[0] | (b[1] << 8) | (b[2] << 16) | (b[3] << 24);
        pk[1] = b[4] | (b[5] << 8) | (b[6] << 16) | (b[7] << 24);
    }
    *reinterpret_cast<uint2v*>(out + (size_t)row * ND + lane * 8) = pk;
}

__device__ inline void topk_insert_i(int (&top)[TOPK], int x) {
    #pragma unroll
    for (int i = 0; i < TOPK; ++i) {
        int mx = top[i] > x ? top[i] : x;
        int mn = top[i] > x ? x : top[i];
        top[i] = mx;
        x = mn;
    }
}

// ---------- fused i8 GEMM + top-10: R18 + 4-slice batched staging ----------
// 512 threads, 8 waves; wave wv owns queries [wv*16, +16) x all 128 n of the tile.
// A panel in registers (af[8], R18). B: FOUR 8-KB K-slice buffers staged in ONE
// batch (4 gl2lds/thread back-to-back -> one latency exposure per 4 K-steps,
// 4x the MLP per drain), then 4x {8 bf ds_reads + 8 MFMA} barrier-free.
// Barriers per block: 32 (was 128). Each sub-buffer keeps the proven 64-B swizzle.
__global__ __launch_bounds__(512, 8)
void knn_chunk(const uchar_t* __restrict__ qb, const uchar_t* __restrict__ dbb,
               int* __restrict__ partial) {
    // XCD swizzle: 16 consecutive logicals (same B-chunk) land on the same XCD
    const int logical = (blockIdx.x & 7) * PERXCD + (blockIdx.x >> 3);
    const int qt = logical & (QTILES - 1);
    const int nc = logical >> 4;       // QTILES == 16
    const int t = threadIdx.x, lane = t & 63, wv = t >> 6;
    const int l15 = lane & 15;
    const int cgrp = lane >> 4;        // logical 16B chunk in a 64-B k-slice

    __shared__ __align__(16) uchar_t Bs[4][128 * 64];    // 32 KB

    // ---- A panel in registers: af[ks] = 16 B of row (qt*128+wv*16+l15), k-slice ks
    int4v af[8];
    {
        const uchar_t* ap = qb + (size_t)(qt * 128 + wv * 16 + l15) * ND + cgrp * 16;
        #pragma unroll
        for (int ks = 0; ks < 8; ++ks)
            af[ks] = *reinterpret_cast<const int4v*>(ap + ks * 64);
    }

    int top[TOPK];
    #pragma unroll
    for (int i = 0; i < TOPK; ++i) top[i] = IMIN;

    const size_t nchunkbase = (size_t)nc * CHUNK_N;

    // ---- hoisted per-lane invariants (R18-identical) ----
    const int srow = t >> 2;
    const int scol = (t & 3) ^ ((srow >> 1) & 3);       // inverse swizzle on global source
    const int soff = srow * ND + scol * 16;
    const int doff = t * 16;
    const int slot = (cgrp ^ ((l15 >> 1) & 3)) * 16;
    const int boff = l15 * 64 + slot;                    // B row = ns*16 + l15 (ns via imm)

    for (int nt = 0; nt < NTILES; ++nt) {
        const uchar_t* bseg = dbb + (nchunkbase + nt * 128) * ND;
        int4v acc[8];
        #pragma unroll
        for (int b = 0; b < 8; ++b) acc[b] = (int4v){0, 0, 0, 0};

        #pragma unroll
        for (int kh = 0; kh < 2; ++kh) {
            __syncthreads();   // previous 4-slice batch's frags consumed
            #pragma unroll
            for (int j = 0; j < 4; ++j)
                GL2LDS(bseg + soff + (kh * 4 + j) * 64, Bs[j] + doff);
            __syncthreads();   // all 4 K-slices staged (implicit vmcnt(0))

            #pragma unroll
            for (int j = 0; j < 4; ++j) {
                const uchar_t* Bj = Bs[j];
                const int ks = kh * 4 + j;
                {
                    int4v bf0 = *reinterpret_cast<const int4v*>(Bj + boff);
                    int4v bf1 = *reinterpret_cast<const int4v*>(Bj + boff + 1024);
                    int4v bf2 = *reinterpret_cast<const int4v*>(Bj + boff + 2048);
                    int4v bf3 = *reinterpret_cast<const int4v*>(Bj + boff + 3072);
                    acc[0] = __builtin_amdgcn_mfma_i32_16x16x64_i8(bf0, af[ks], acc[0], 0, 0, 0);
                    acc[1] = __builtin_amdgcn_mfma_i32_16x16x64_i8(bf1, af[ks], acc[1], 0, 0, 0);
                    acc[2] = __builtin_amdgcn_mfma_i32_16x16x64_i8(bf2, af[ks], acc[2], 0, 0, 0);
                    acc[3] = __builtin_amdgcn_mfma_i32_16x16x64_i8(bf3, af[ks], acc[3], 0, 0, 0);
                }
                {
                    int4v bf4 = *reinterpret_cast<const int4v*>(Bj + boff + 4096);
                    int4v bf5 = *reinterpret_cast<const int4v*>(Bj + boff + 5120);
                    int4v bf6 = *reinterpret_cast<const int4v*>(Bj + boff + 6144);
                    int4v bf7 = *reinterpret_cast<const int4v*>(Bj + boff + 7168);
                    acc[4] = __builtin_amdgcn_mfma_i32_16x16x64_i8(bf4, af[ks], acc[4], 0, 0, 0);
                    acc[5] = __builtin_amdgcn_mfma_i32_16x16x64_i8(bf5, af[ks], acc[5], 0, 0, 0);
                    acc[6] = __builtin_amdgcn_mfma_i32_16x16x64_i8(bf6, af[ks], acc[6], 0, 0, 0);
                    acc[7] = __builtin_amdgcn_mfma_i32_16x16x64_i8(bf7, af[ks], acc[7], 0, 0, 0);
                }
            }
        }

        // integer selection: 32 candidates for this thread's single query
        int m = acc[0][0];
        #pragma unroll
        for (int ns = 0; ns < 8; ++ns)
            #pragma unroll
            for (int r = 0; r < 4; ++r)
                m = m > acc[ns][r] ? m : acc[ns][r];
        if (m > top[TOPK - 1]) {
            #pragma unroll
            for (int ns = 0; ns < 8; ++ns)
                #pragma unroll
                for (int r = 0; r < 4; ++r) {
                    int v = acc[ns][r];
                    if (v > top[TOPK - 1]) topk_insert_i(top, v);
                }
        }
    }

    // butterfly merge across the 4 lanes sharing each query (lane ^ 16, lane ^ 32)
    #pragma unroll
    for (int step = 16; step <= 32; step <<= 1) {
        int other[TOPK];
        #pragma unroll
        for (int i = 0; i < TOPK; ++i) other[i] = __shfl_xor(top[i], step, 64);
        #pragma unroll
        for (int i = 0; i < TOPK; ++i)
            if (other[i] > top[TOPK - 1]) topk_insert_i(top, other[i]);
    }

    // lanes 0..15 hold the final per-query top-10 for q = qt*128 + wv*16 + l15
    if (cgrp == 0) {
        const int q = qt * 128 + wv * 16 + l15;
        int* dst = partial + ((size_t)nc * NQ + q) * TOPK;
        #pragma unroll
        for (int i = 0; i < TOPK; ++i) dst[i] = top[i];
    }
}

// ---------- merge NCHUNK chunks per query (int domain), emit k-th squared distance ----------
__global__ void final_merge(const int* __restrict__ partial, float* __restrict__ out) {
    const int q = blockIdx.x * 4 + (threadIdx.x >> 6);
    const int lane = threadIdx.x & 63;
    if (q >= NQ) return;
    int top[TOPK];
    #pragma unroll
    for (int i = 0; i < TOPK; ++i) top[i] = IMIN;
    for (int c = lane; c < NCHUNK; c += 64) {
        const int* p = partial + ((size_t)c * NQ + q) * TOPK;
        #pragma unroll
        for (int i = 0; i < TOPK; ++i) {
            int x = p[i];
            if (x > top[TOPK - 1]) topk_insert_i(top, x);
        }
    }
    #pragma unroll
    for (int step = 1; step <= 32; step <<= 1) {
        int other[TOPK];
        #pragma unroll
        for (int i = 0; i < TOPK; ++i) other[i] = __shfl_xor(top[i], step, 64);
        #pragma unroll
        for (int i = 0; i < TOPK; ++i)
            if (other[i] > top[TOPK - 1]) topk_insert_i(top, other[i]);
    }
    if (lane == 0) out[q] = 2.0f - 2.0f * ((float)top[TOPK - 1] * QINV);
}

extern "C" void kernel_launch(void* const* d_in, const int* in_sizes, int n_in,
                              void* d_out, int out_size, void* d_ws, size_t ws_size,
                              hipStream_t stream) {
    const float* features = (const float*)d_in[0];
    const float* dbf      = (const float*)d_in[2];
    float* out = (float*)d_out;

    uchar_t* dbb = (uchar_t*)d_ws;                           // [NPAD][512] i8     ~51.4 MB
    uchar_t* qbn = dbb + (size_t)NPAD * ND;                  // [2048][512] i8     ~1 MB
    int* partial = (int*)(qbn + (size_t)NQ * ND);            // [NCHUNK][2048][10] ~8.0 MB

    normalize_rows_i8<<<NPAD / 4, 256, 0, stream>>>(dbf, dbb, NDB, NPAD);
    normalize_rows_i8<<<NQ / 4, 256, 0, stream>>>(features, qbn, NQ, NQ);
    knn_chunk<<<NWG, 512, 0, stream>>>(qbn, dbb, partial);
    final_merge<<<NQ / 4, 256, 0, stream>>>(partial, out);
}